// Round 11
// baseline (36.117 us; speedup 1.0000x reference)
//
#include <hip/hip_runtime.h>

#define S_LEN 4096
#define DIM   64
#define HALF  50
#define RB    64            // query rows per block (4 waves x 16 rows)
#define WQ    16
#define THREADS 256
#define SCALE 0.125f

typedef __attribute__((ext_vector_type(8))) short bf16x8;
typedef __attribute__((ext_vector_type(4))) float f32x4;

__device__ __forceinline__ unsigned int bf16_rne(float f) {
    unsigned int u = __float_as_uint(f);
    return (u + 0x7fffu + ((u >> 16) & 1u)) >> 16;
}
__device__ __forceinline__ unsigned int pk2(float lo, float hi) {
    return bf16_rne(lo) | (bf16_rne(hi) << 16);
}
__device__ __forceinline__ bf16x8 cvt8(float4 a, float4 b) {
    uint4 t = make_uint4(pk2(a.x, a.y), pk2(a.z, a.w), pk2(b.x, b.y), pk2(b.z, b.w));
    return __builtin_bit_cast(bf16x8, t);
}

// Fully streaming banded attention: NO K/V LDS staging, NO __syncthreads.
// K read as MFMA A-frags (32B/lane contiguous), V^T as A-frags via 4B/lane
// gather (wave touches 4x64B segments per instr), out-of-range keys CLAMPED
// (band mask zeroes their P, so clamped garbage contributes 0). K/V reuse
// (~7x) served by L1/L2 (per-XCD slice = 2 heads = 4MB = L2). 4-wave blocks,
// no barriers -> phases drift freely, TLP hides latency.
__global__ __launch_bounds__(THREADS, 4)
void lattn_stream(const float* __restrict__ Q, const float* __restrict__ K,
                  const float* __restrict__ V, float* __restrict__ O) {
    __shared__ unsigned short Ps[4][16 * 40];   // per-wave P scratch only (5KB)

    // bijective XCD swizzle: consecutive r0-blocks (sliding windows) share an XCD L2
    const int nwg = gridDim.x;                 // 1024
    const int cpx = nwg >> 3;
    const int bid = blockIdx.x;
    const int logical = (bid & 7) * cpx + (bid >> 3);
    const int bh = logical >> 6;               // 64 x-blocks per bh
    const int r0 = (logical & 63) * RB;

    const size_t base = (size_t)bh * (S_LEN * DIM);
    const float* Qg = Q + base;
    const float* Kg = K + base;
    const float* Vg = V + base;
    float*       Og = O + base;

    const int u = threadIdx.x;
    const int lane = u & 63;
    const int wv_  = u >> 6;
    const int g  = lane >> 4;
    const int cc = lane & 15;
    const int qlo = r0 + WQ * wv_;

    // ---- Q^T B-fragments from global (scale folded) ----
    bf16x8 qf[2];
    #pragma unroll
    for (int ds = 0; ds < 2; ++ds) {
        const float* src = Qg + (size_t)(qlo + cc) * DIM + ds * 32 + g * 8;
        float4 a = *(const float4*)src;
        float4 b = *(const float4*)(src + 4);
        a.x*=SCALE; a.y*=SCALE; a.z*=SCALE; a.w*=SCALE;
        b.x*=SCALE; b.y*=SCALE; b.z*=SCALE; b.w*=SCALE;
        qf[ds] = cvt8(a, b);
    }

    // ---- global-key tile range for this wave ----
    const int lo = (qlo >= HALF) ? ((qlo - HALF) & ~31) : 0;
    const int t0 = lo >> 5;
    const int hi = min(S_LEN, qlo + WQ - 1 + HALF + 1);
    const int t1 = (hi + 31) >> 5;

    unsigned short* Pw = Ps[wv_];
    f32x4 oacc[4] = {};
    float denom = 0.f;

    for (int st = t0; st < t1; ++st) {
        const int kb32 = st << 5;

        // --- K tile A-frags straight from global (clamped rows) ---
        bf16x8 ka[2][2];
        #pragma unroll
        for (int kt = 0; kt < 2; ++kt) {
            const int krow = min(kb32 + kt * 16 + cc, S_LEN - 1);
            const float* kp = Kg + (size_t)krow * DIM + g * 8;
            const float4 a0 = *(const float4*)kp;
            const float4 a1 = *(const float4*)(kp + 4);
            const float4 b0 = *(const float4*)(kp + 32);
            const float4 b1 = *(const float4*)(kp + 36);
            ka[0][kt] = cvt8(a0, a1);
            ka[1][kt] = cvt8(b0, b1);
        }

        // --- V^T tile A-frags via 4B/lane gather (issued early, independent of QK) ---
        const int kv = kb32 + g * 8;
        bf16x8 vf[4];
        #pragma unroll
        for (int dt = 0; dt < 4; ++dt) {
            float w0[4], w1[4];
            #pragma unroll
            for (int j = 0; j < 4; ++j) {
                const int key0 = min(kv + j,     S_LEN - 1);
                const int key1 = min(kv + j + 4, S_LEN - 1);
                w0[j] = Vg[(size_t)key0 * DIM + dt * 16 + cc];
                w1[j] = Vg[(size_t)key1 * DIM + dt * 16 + cc];
            }
            vf[dt] = cvt8(make_float4(w0[0], w0[1], w0[2], w0[3]),
                          make_float4(w1[0], w1[1], w1[2], w1[3]));
        }

        // --- swapped QK^T: S^T[key][q] ---
        f32x4 sacc[2] = {};
        #pragma unroll
        for (int ds = 0; ds < 2; ++ds) {
            #pragma unroll
            for (int kt = 0; kt < 2; ++kt)
                sacc[kt] = __builtin_amdgcn_mfma_f32_16x16x32_bf16(ka[ds][kt], qf[ds], sacc[kt], 0, 0, 0);
        }

        // --- mask + exp + P layout shuffle (per-wave LDS, wave-internal only) ---
        const int q = qlo + cc;
        #pragma unroll
        for (int kt = 0; kt < 2; ++kt) {
            float w4[4];
            const int keyb = kb32 + kt * 16 + g * 4;
            #pragma unroll
            for (int r = 0; r < 4; ++r) {
                const int key = keyb + r;
                const float e = __expf(fminf(sacc[kt][r], 60.f));
                const int dd  = key - q;
                const bool ok = (dd >= -HALF) && (dd <= HALF) && (key < S_LEN);
                w4[r] = ok ? e : 0.f;
                denom += w4[r];
            }
            *(uint2*)(Pw + cc * 40 + kt * 16 + g * 4) =
                make_uint2(pk2(w4[0], w4[1]), pk2(w4[2], w4[3]));
        }
        const bf16x8 pf = *(const bf16x8*)(Pw + cc * 40 + g * 8);

        // --- PV: O^T += V^T x P ---
        #pragma unroll
        for (int dt = 0; dt < 4; ++dt)
            oacc[dt] = __builtin_amdgcn_mfma_f32_16x16x32_bf16(vf[dt], pf, oacc[dt], 0, 0, 0);
    }

    // ---- normalize + store ----
    denom += __shfl_xor(denom, 16);
    denom += __shfl_xor(denom, 32);
    const float rinv = 1.f / denom;
    float* dst = Og + (size_t)(qlo + cc) * DIM;
    #pragma unroll
    for (int dt = 0; dt < 4; ++dt) {
        const f32x4 o = oacc[dt];
        *(float4*)(dst + dt * 16 + g * 4) =
            make_float4(o[0] * rinv, o[1] * rinv, o[2] * rinv, o[3] * rinv);
    }
}

extern "C" void kernel_launch(void* const* d_in, const int* in_sizes, int n_in,
                              void* d_out, int out_size, void* d_ws, size_t ws_size,
                              hipStream_t stream) {
    const float* q = (const float*)d_in[0];
    const float* k = (const float*)d_in[1];
    const float* v = (const float*)d_in[2];
    float* o = (float*)d_out;
    const int nbh = in_sizes[0] / (S_LEN * DIM);      // B*H = 16
    dim3 grid((S_LEN / RB) * nbh);                    // 1024 blocks, 4 waves each
    lattn_stream<<<grid, THREADS, 0, stream>>>(q, k, v, o);
}